// Round 1
// baseline (272.883 us; speedup 1.0000x reference)
//
#include <hip/hip_runtime.h>

#define HH 64
#define WW 64

// workspace float offsets
#define WREP_OFF 0        // [n][kh][kw][dd][c][d]  : 36864
#define AREP_OFF 36864    // [n][o][d][c]           : 4096
#define FWREP_OFF 40960   // [n][k][d][j]           : 4608
#define CWREP_OFF 45568   // [n][d][j]              : 512
#define PREP_N 46080
#define VT_OFF 46080      // v in vt layout [b][h][w][n*8+d] : 8388608 floats

__global__ __launch_bounds__(256) void prep_kernel(
    const float* __restrict__ attw, const float* __restrict__ ctw,
    const float* __restrict__ few, const float* __restrict__ caw,
    float* __restrict__ ws) {
  int i = blockIdx.x * 256 + threadIdx.x;
  if (i >= PREP_N) return;
  if (i < AREP_OFF) {
    // Wrep[n][kh][kw][dd][c][d] = ConvTrans_W[kh,kw,dd, c*64+d*8+n]
    int d = i & 7, c = (i >> 3) & 7, dd = (i >> 6) & 7;
    int r = i >> 9; int kw = r % 3; int r2 = r / 3; int kh = r2 % 3; int n = r2 / 3;
    ws[i] = ctw[(((kh * 3 + kw) * 8 + dd) * 512) + c * 64 + d * 8 + n];
  } else if (i < FWREP_OFF) {
    // Arep[n][o][d][c] = Att_W[0,0,d,c, n*8+o]
    int j = i - AREP_OFF;
    int c = j & 7, d = (j >> 3) & 7, o = (j >> 6) & 7, n = (j >> 9) & 7;
    ws[i] = attw[d * 512 + c * 64 + n * 8 + o];
  } else if (i < CWREP_OFF) {
    // FWrep[n][k][d][j] = FeaExt_W[kh,kw,d, n*8+j], k = kh*3+kw
    int j = i - FWREP_OFF;
    int jj = j & 7, d = (j >> 3) & 7; int r = j >> 6; int k = r % 9; int n = r / 9;
    ws[i] = few[(k * 8 + d) * 64 + n * 8 + jj];
  } else {
    // CWrep[n][d][j] = CapsAct_W[0,0,d, n*8+j]
    int j = i - CWREP_OFF;
    int jj = j & 7, d = (j >> 3) & 7, n = (j >> 6) & 7;
    ws[i] = caw[d * 64 + n * 8 + jj];
  }
}

// Stage 1: ConvTrans + attention + softmax + weighted sum -> vt[b,h,w,n*8+d]
// Block: 256 threads = 4 waves; tile 8x8 pixels, halo 10x10.
// Wave w handles n in {w, w+4}; lane = pixel (py=lane>>3, px=lane&7).
__global__ __launch_bounds__(256) void caps_stage1(
    const float* __restrict__ in, const float* __restrict__ ws,
    const float* __restrict__ ctb, float* __restrict__ vt) {
  __shared__ float tile[100 * 68];  // pixel stride 68 floats (bank-conflict-free)
  int bid = blockIdx.x;
  int b = bid >> 6;
  int t = bid & 63;
  int ty = t >> 3, tx = t & 7;
  int y0 = ty * 8 - 1, x0 = tx * 8 - 1;
  int tid = threadIdx.x;

  // cooperative tile load: 100 pixels x 16 float4, zero-pad outside image
  for (int i = tid; i < 1600; i += 256) {
    int p = i >> 4, q = i & 15;
    int py = p / 10, px = p % 10;
    int gy = y0 + py, gx = x0 + px;
    float4 val = make_float4(0.f, 0.f, 0.f, 0.f);
    if (gy >= 0 && gy < HH && gx >= 0 && gx < WW)
      val = *(const float4*)(in + ((b * HH + gy) * WW + gx) * 64 + q * 4);
    *(float4*)&tile[p * 68 + q * 4] = val;
  }
  __syncthreads();

  int wv = __builtin_amdgcn_readfirstlane(tid >> 6);
  int lane = tid & 63;
  int py = lane >> 3, px = lane & 7;
  const float* wrep = ws + WREP_OFF;
  const float* arep = ws + AREP_OFF;
  int pixout = ((b * HH + (ty * 8 + py)) * WW + (tx * 8 + px)) * 64;

#pragma unroll 1
  for (int nn = 0; nn < 2; ++nn) {
    int n = wv + nn * 4;
    float u[8][8];  // [d][c]
#pragma unroll
    for (int d = 0; d < 8; ++d)
#pragma unroll
      for (int c = 0; c < 8; ++c) u[d][c] = ctb[c * 64 + d * 8 + n];

#pragma unroll 1
    for (int k = 0; k < 9; ++k) {
      int kh = k / 3, kw = k % 3;
      const float* wp = wrep + (n * 9 + k) * 512;  // [dd][c][d]
      int tb = ((py + kh) * 10 + (px + kw)) * 68;
#pragma unroll
      for (int dd = 0; dd < 8; ++dd) {
        float4 xa = *(const float4*)&tile[tb + dd * 8];
        float4 xb = *(const float4*)&tile[tb + dd * 8 + 4];
        float xs[8] = {xa.x, xa.y, xa.z, xa.w, xb.x, xb.y, xb.z, xb.w};
#pragma unroll
        for (int c = 0; c < 8; ++c)
#pragma unroll
          for (int d = 0; d < 8; ++d)
            u[d][c] = fmaf(xs[c], wp[(dd * 8 + c) * 8 + d], u[d][c]);
      }
    }

    // attention logits + softmax over input types
    float att[8];
#pragma unroll
    for (int o = 0; o < 8; ++o) {
      const float* ap = arep + (n * 8 + o) * 64;  // [d*8+c]
      float s = 0.f;
#pragma unroll
      for (int d = 0; d < 8; ++d)
#pragma unroll
        for (int c = 0; c < 8; ++c) s = fmaf(u[d][c], ap[d * 8 + c], s);
      att[o] = s;
    }
    float m = att[0];
#pragma unroll
    for (int o = 1; o < 8; ++o) m = fmaxf(m, att[o]);
    float ssum = 0.f;
#pragma unroll
    for (int o = 0; o < 8; ++o) { att[o] = __expf(att[o] - m); ssum += att[o]; }
    float inv = 1.0f / ssum;
#pragma unroll
    for (int o = 0; o < 8; ++o) att[o] *= inv;

    // v[d] = sum_c u[d][c] * att[c]
    float v[8];
#pragma unroll
    for (int d = 0; d < 8; ++d) {
      float s = 0.f;
#pragma unroll
      for (int c = 0; c < 8; ++c) s = fmaf(u[d][c], att[c], s);
      v[d] = s;
    }
    float4* dst = (float4*)(vt + pixout + n * 8);
    dst[0] = make_float4(v[0], v[1], v[2], v[3]);
    dst[1] = make_float4(v[4], v[5], v[6], v[7]);
  }
}

// Stage 2: FeaExt (3x3 grouped) + ReLU + CapsAct (1x1 grouped) -> out[b,h,w,dim*8+n]
__global__ __launch_bounds__(256) void caps_stage2(
    const float* __restrict__ vt, const float* __restrict__ ws,
    const float* __restrict__ fb, const float* __restrict__ cab,
    float* __restrict__ out) {
  __shared__ float tile[100 * 68];
  int bid = blockIdx.x;
  int b = bid >> 6;
  int t = bid & 63;
  int ty = t >> 3, tx = t & 7;
  int y0 = ty * 8 - 1, x0 = tx * 8 - 1;
  int tid = threadIdx.x;

  for (int i = tid; i < 1600; i += 256) {
    int p = i >> 4, q = i & 15;
    int py = p / 10, px = p % 10;
    int gy = y0 + py, gx = x0 + px;
    float4 val = make_float4(0.f, 0.f, 0.f, 0.f);
    if (gy >= 0 && gy < HH && gx >= 0 && gx < WW)
      val = *(const float4*)(vt + ((b * HH + gy) * WW + gx) * 64 + q * 4);
    *(float4*)&tile[p * 68 + q * 4] = val;
  }
  __syncthreads();

  int wv = __builtin_amdgcn_readfirstlane(tid >> 6);
  int lane = tid & 63;
  int py = lane >> 3, px = lane & 7;
  const float* fwrep = ws + FWREP_OFF;
  const float* cwrep = ws + CWREP_OFF;
  int pixout = ((b * HH + (ty * 8 + py)) * WW + (tx * 8 + px)) * 64;

#pragma unroll 1
  for (int nn = 0; nn < 2; ++nn) {
    int n = wv + nn * 4;
    float h1[8];
#pragma unroll
    for (int j = 0; j < 8; ++j) h1[j] = fb[n * 8 + j];

#pragma unroll 1
    for (int k = 0; k < 9; ++k) {
      int kh = k / 3, kw = k % 3;
      const float* wp = fwrep + (n * 9 + k) * 64;  // [d][j]
      int tb = ((py + kh) * 10 + (px + kw)) * 68 + n * 8;
      float4 xa = *(const float4*)&tile[tb];
      float4 xb = *(const float4*)&tile[tb + 4];
      float xs[8] = {xa.x, xa.y, xa.z, xa.w, xb.x, xb.y, xb.z, xb.w};
#pragma unroll
      for (int d = 0; d < 8; ++d)
#pragma unroll
        for (int j = 0; j < 8; ++j)
          h1[j] = fmaf(xs[d], wp[d * 8 + j], h1[j]);
    }
#pragma unroll
    for (int j = 0; j < 8; ++j) h1[j] = fmaxf(h1[j], 0.f);

    float h2[8];
#pragma unroll
    for (int j = 0; j < 8; ++j) h2[j] = cab[n * 8 + j];
#pragma unroll
    for (int d = 0; d < 8; ++d)
#pragma unroll
      for (int j = 0; j < 8; ++j)
        h2[j] = fmaf(h1[d], cwrep[n * 64 + d * 8 + j], h2[j]);

#pragma unroll
    for (int j = 0; j < 8; ++j) out[pixout + j * 8 + n] = h2[j];
  }
}

extern "C" void kernel_launch(void* const* d_in, const int* in_sizes, int n_in,
                              void* d_out, int out_size, void* d_ws, size_t ws_size,
                              hipStream_t stream) {
  const float* inputs = (const float*)d_in[0];
  const float* attw   = (const float*)d_in[1];
  const float* ctw    = (const float*)d_in[2];
  const float* ctb    = (const float*)d_in[3];
  const float* few    = (const float*)d_in[4];
  const float* fb     = (const float*)d_in[5];
  const float* caw    = (const float*)d_in[6];
  const float* cab    = (const float*)d_in[7];
  float* out = (float*)d_out;
  float* ws  = (float*)d_ws;
  float* vt  = ws + VT_OFF;

  prep_kernel<<<(PREP_N + 255) / 256, 256, 0, stream>>>(attw, ctw, few, caw, ws);
  caps_stage1<<<32 * 64, 256, 0, stream>>>(inputs, ws, ctb, vt);
  caps_stage2<<<32 * 64, 256, 0, stream>>>(vt, ws, fb, cab, out);
}

// Round 2
// 271.332 us; speedup vs baseline: 1.0057x; 1.0057x over previous
//
#include <hip/hip_runtime.h>

#define HH 64
#define WW 64

// workspace float offsets
#define WREP_OFF 0        // [n][kh][kw][dd][c][d]  : 36864
#define AREP_OFF 36864    // [n][o][d][c]           : 4096
#define FWREP_OFF 40960   // [n][k][d][j]           : 4608
#define CWREP_OFF 45568   // [n][d][j]              : 512
#define PREP_N 46080
#define VT_OFF 46080      // v in vt layout [b][h][w][n*8+d] : 8388608 floats

__global__ __launch_bounds__(256) void prep_kernel(
    const float* __restrict__ attw, const float* __restrict__ ctw,
    const float* __restrict__ few, const float* __restrict__ caw,
    float* __restrict__ ws) {
  int i = blockIdx.x * 256 + threadIdx.x;
  if (i >= PREP_N) return;
  if (i < AREP_OFF) {
    int d = i & 7, c = (i >> 3) & 7, dd = (i >> 6) & 7;
    int r = i >> 9; int kw = r % 3; int r2 = r / 3; int kh = r2 % 3; int n = r2 / 3;
    ws[i] = ctw[(((kh * 3 + kw) * 8 + dd) * 512) + c * 64 + d * 8 + n];
  } else if (i < FWREP_OFF) {
    int j = i - AREP_OFF;
    int c = j & 7, d = (j >> 3) & 7, o = (j >> 6) & 7, n = (j >> 9) & 7;
    ws[i] = attw[d * 512 + c * 64 + n * 8 + o];
  } else if (i < CWREP_OFF) {
    int j = i - FWREP_OFF;
    int jj = j & 7, d = (j >> 3) & 7; int r = j >> 6; int k = r % 9; int n = r / 9;
    ws[i] = few[(k * 8 + d) * 64 + n * 8 + jj];
  } else {
    int j = i - CWREP_OFF;
    int jj = j & 7, d = (j >> 3) & 7, n = (j >> 6) & 7;
    ws[i] = caw[d * 64 + n * 8 + jj];
  }
}

// XOR-swizzled tile: pixel p's float4-chunk m (floats m*4..m*4+3) lives at
// p*64 + ((m+p)&15)*4. Every wave-level b128 access (fill, dd-reads, n-reads,
// writeback) then spreads over all 32 banks -> conflict-free (8-cyc floor).

// Stage 1: ConvTrans + attention + softmax + weighted sum -> vt[b,h,w,n*8+d]
__global__ __launch_bounds__(256, 4) void caps_stage1(
    const float* __restrict__ in, const float* __restrict__ ws,
    const float* __restrict__ ctb, float* __restrict__ vt) {
  __shared__ float tile[100 * 64];
  int bid = blockIdx.x;
  int b = bid >> 6;
  int t = bid & 63;
  int ty = t >> 3, tx = t & 7;
  int y0 = ty * 8 - 1, x0 = tx * 8 - 1;
  int tid = threadIdx.x;

  for (int i = tid; i < 1600; i += 256) {
    int p = i >> 4, q = i & 15;
    int py = p / 10, px = p % 10;
    int gy = y0 + py, gx = x0 + px;
    float4 val = make_float4(0.f, 0.f, 0.f, 0.f);
    if (gy >= 0 && gy < HH && gx >= 0 && gx < WW)
      val = *(const float4*)(in + ((b * HH + gy) * WW + gx) * 64 + q * 4);
    *(float4*)&tile[p * 64 + ((q + p) & 15) * 4] = val;
  }
  __syncthreads();

  int wv = __builtin_amdgcn_readfirstlane(tid >> 6);
  int lane = tid & 63;
  int py = lane >> 3, px = lane & 7;
  int p0 = py * 10 + px;
  const float* wrep = ws + WREP_OFF;
  const float* arep = ws + AREP_OFF;
  int pixout = ((b * HH + (ty * 8 + py)) * WW + (tx * 8 + px)) * 64;

#pragma unroll 1
  for (int nn = 0; nn < 2; ++nn) {
    int n = wv + nn * 4;
    float u[8][8];  // [d][c]
#pragma unroll
    for (int d = 0; d < 8; ++d)
#pragma unroll
      for (int c = 0; c < 8; ++c) u[d][c] = ctb[c * 64 + d * 8 + n];

#pragma unroll 1
    for (int k = 0; k < 9; ++k) {
      int kh = k / 3, kw = k % 3;
      int pk = p0 + kh * 10 + kw;
      const float* wp = wrep + (n * 9 + k) * 512;  // [dd][c][d]
      int pb = pk * 64;
#pragma unroll
      for (int dd = 0; dd < 8; ++dd) {
        float4 xa = *(const float4*)&tile[pb + ((2 * dd + pk) & 15) * 4];
        float4 xb = *(const float4*)&tile[pb + ((2 * dd + 1 + pk) & 15) * 4];
        float xs[8] = {xa.x, xa.y, xa.z, xa.w, xb.x, xb.y, xb.z, xb.w};
#pragma unroll
        for (int c = 0; c < 8; ++c)
#pragma unroll
          for (int d = 0; d < 8; ++d)
            u[d][c] = fmaf(xs[c], wp[(dd * 8 + c) * 8 + d], u[d][c]);
      }
    }

    float att[8];
#pragma unroll
    for (int o = 0; o < 8; ++o) {
      const float* ap = arep + (n * 8 + o) * 64;
      float s = 0.f;
#pragma unroll
      for (int d = 0; d < 8; ++d)
#pragma unroll
        for (int c = 0; c < 8; ++c) s = fmaf(u[d][c], ap[d * 8 + c], s);
      att[o] = s;
    }
    float m = att[0];
#pragma unroll
    for (int o = 1; o < 8; ++o) m = fmaxf(m, att[o]);
    float ssum = 0.f;
#pragma unroll
    for (int o = 0; o < 8; ++o) { att[o] = __expf(att[o] - m); ssum += att[o]; }
    float inv = 1.0f / ssum;
#pragma unroll
    for (int o = 0; o < 8; ++o) att[o] *= inv;

    float v[8];
#pragma unroll
    for (int d = 0; d < 8; ++d) {
      float s = 0.f;
#pragma unroll
      for (int c = 0; c < 8; ++c) s = fmaf(u[d][c], att[c], s);
      v[d] = s;
    }
    float4* dst = (float4*)(vt + pixout + n * 8);
    dst[0] = make_float4(v[0], v[1], v[2], v[3]);
    dst[1] = make_float4(v[4], v[5], v[6], v[7]);
  }
}

// Stage 2: FeaExt (3x3 grouped) + ReLU + CapsAct (1x1 grouped) -> out
// Epilogue: h2 transposed through (reused) LDS tile, coalesced float4 stores.
__global__ __launch_bounds__(256, 4) void caps_stage2(
    const float* __restrict__ vt, const float* __restrict__ ws,
    const float* __restrict__ fb, const float* __restrict__ cab,
    float* __restrict__ out) {
  __shared__ float tile[100 * 64];
  int bid = blockIdx.x;
  int b = bid >> 6;
  int t = bid & 63;
  int ty = t >> 3, tx = t & 7;
  int y0 = ty * 8 - 1, x0 = tx * 8 - 1;
  int tid = threadIdx.x;

  for (int i = tid; i < 1600; i += 256) {
    int p = i >> 4, q = i & 15;
    int py = p / 10, px = p % 10;
    int gy = y0 + py, gx = x0 + px;
    float4 val = make_float4(0.f, 0.f, 0.f, 0.f);
    if (gy >= 0 && gy < HH && gx >= 0 && gx < WW)
      val = *(const float4*)(vt + ((b * HH + gy) * WW + gx) * 64 + q * 4);
    *(float4*)&tile[p * 64 + ((q + p) & 15) * 4] = val;
  }
  __syncthreads();

  int wv = __builtin_amdgcn_readfirstlane(tid >> 6);
  int lane = tid & 63;
  int py = lane >> 3, px = lane & 7;
  int p0 = py * 10 + px;
  const float* fwrep = ws + FWREP_OFF;
  const float* cwrep = ws + CWREP_OFF;

  float h2s[2][8];
#pragma unroll 1
  for (int nn = 0; nn < 2; ++nn) {
    int n = wv + nn * 4;
    float h1[8];
#pragma unroll
    for (int j = 0; j < 8; ++j) h1[j] = fb[n * 8 + j];

#pragma unroll 1
    for (int k = 0; k < 9; ++k) {
      int kh = k / 3, kw = k % 3;
      int pk = p0 + kh * 10 + kw;
      const float* wp = fwrep + (n * 9 + k) * 64;  // [d][j]
      int pb = pk * 64;
      float4 xa = *(const float4*)&tile[pb + ((2 * n + pk) & 15) * 4];
      float4 xb = *(const float4*)&tile[pb + ((2 * n + 1 + pk) & 15) * 4];
      float xs[8] = {xa.x, xa.y, xa.z, xa.w, xb.x, xb.y, xb.z, xb.w};
#pragma unroll
      for (int d = 0; d < 8; ++d)
#pragma unroll
        for (int j = 0; j < 8; ++j)
          h1[j] = fmaf(xs[d], wp[d * 8 + j], h1[j]);
    }
#pragma unroll
    for (int j = 0; j < 8; ++j) h1[j] = fmaxf(h1[j], 0.f);

#pragma unroll
    for (int j = 0; j < 8; ++j) h2s[nn][j] = cab[n * 8 + j];
#pragma unroll
    for (int d = 0; d < 8; ++d)
#pragma unroll
      for (int j = 0; j < 8; ++j)
        h2s[nn][j] = fmaf(h1[d], cwrep[n * 64 + d * 8 + j], h2s[nn][j]);
  }

  __syncthreads();  // all tile reads done; reuse tile for output transpose
  int pix = py * 8 + px;
#pragma unroll
  for (int nn = 0; nn < 2; ++nn) {
    int n = wv + nn * 4;
#pragma unroll
    for (int j = 0; j < 8; ++j) {
      int m = 2 * j + (n >> 2);
      tile[pix * 64 + ((m + pix) & 15) * 4 + (n & 3)] = h2s[nn][j];
    }
  }
  __syncthreads();

  for (int slot = tid; slot < 1024; slot += 256) {
    int p = slot >> 4, q = slot & 15;
    float4 val = *(const float4*)&tile[p * 64 + ((q + p) & 15) * 4];
    int gpy = p >> 3, gpx = p & 7;
    *(float4*)(out + ((b * HH + (ty * 8 + gpy)) * WW + (tx * 8 + gpx)) * 64 + q * 4) = val;
  }
}

extern "C" void kernel_launch(void* const* d_in, const int* in_sizes, int n_in,
                              void* d_out, int out_size, void* d_ws, size_t ws_size,
                              hipStream_t stream) {
  const float* inputs = (const float*)d_in[0];
  const float* attw   = (const float*)d_in[1];
  const float* ctw    = (const float*)d_in[2];
  const float* ctb    = (const float*)d_in[3];
  const float* few    = (const float*)d_in[4];
  const float* fb     = (const float*)d_in[5];
  const float* caw    = (const float*)d_in[6];
  const float* cab    = (const float*)d_in[7];
  float* out = (float*)d_out;
  float* ws  = (float*)d_ws;
  float* vt  = ws + VT_OFF;

  prep_kernel<<<(PREP_N + 255) / 256, 256, 0, stream>>>(attw, ctw, few, caw, ws);
  caps_stage1<<<32 * 64, 256, 0, stream>>>(inputs, ws, ctb, vt);
  caps_stage2<<<32 * 64, 256, 0, stream>>>(vt, ws, fb, cab, out);
}

// Round 3
// 253.975 us; speedup vs baseline: 1.0744x; 1.0683x over previous
//
#include <hip/hip_runtime.h>
#include <hip/hip_fp16.h>

#define HH 64
#define WW 64

// workspace float offsets
#define WREP_OFF 0        // [n][kh][kw][dd][c][d]  : 36864
#define AREP_OFF 36864    // [n][o][d][c]           : 4096
#define FWREP_OFF 40960   // [n][k][d][j]           : 4608
#define CWREP_OFF 45568   // [n][d][j]              : 512
#define PREP_N 46080
#define VT_OFF 46080      // v as fp16, layout [pixel][(n,d)] : 131072*64 halves

union F4H8 { float4 f4; __half h[8]; };

__global__ __launch_bounds__(256) void prep_kernel(
    const float* __restrict__ attw, const float* __restrict__ ctw,
    const float* __restrict__ few, const float* __restrict__ caw,
    float* __restrict__ ws) {
  int i = blockIdx.x * 256 + threadIdx.x;
  if (i >= PREP_N) return;
  if (i < AREP_OFF) {
    int d = i & 7, c = (i >> 3) & 7, dd = (i >> 6) & 7;
    int r = i >> 9; int kw = r % 3; int r2 = r / 3; int kh = r2 % 3; int n = r2 / 3;
    ws[i] = ctw[(((kh * 3 + kw) * 8 + dd) * 512) + c * 64 + d * 8 + n];
  } else if (i < FWREP_OFF) {
    int j = i - AREP_OFF;
    int c = j & 7, d = (j >> 3) & 7, o = (j >> 6) & 7, n = (j >> 9) & 7;
    ws[i] = attw[d * 512 + c * 64 + n * 8 + o];
  } else if (i < CWREP_OFF) {
    int j = i - FWREP_OFF;
    int jj = j & 7, d = (j >> 3) & 7; int r = j >> 6; int k = r % 9; int n = r / 9;
    ws[i] = few[(k * 8 + d) * 64 + n * 8 + jj];
  } else {
    int j = i - CWREP_OFF;
    int jj = j & 7, d = (j >> 3) & 7, n = (j >> 6) & 7;
    ws[i] = caw[d * 64 + n * 8 + jj];
  }
}

// Stage 1: ConvTrans + attention + softmax + weighted sum -> vt (fp16)
// 512 threads = 8 waves; wave w owns output type n=w; lane = pixel of 8x8 tile.
// Hot tile: linear, pixel stride 68 floats (immediate-offset friendly, b128-floor banks).
__global__ __launch_bounds__(512, 4) void caps_stage1(
    const float* __restrict__ in, const float* __restrict__ ws,
    const float* __restrict__ ctb, __half* __restrict__ vt) {
  __shared__ float tile[100 * 68];  // 27.2 KB
  int bid = blockIdx.x;
  int b = bid >> 6;
  int t = bid & 63;
  int ty = t >> 3, tx = t & 7;
  int y0 = ty * 8 - 1, x0 = tx * 8 - 1;
  int tid = threadIdx.x;

  for (int i = tid; i < 1600; i += 512) {
    int p = i >> 4, q = i & 15;
    int py = p / 10, px = p % 10;
    int gy = y0 + py, gx = x0 + px;
    float4 val = make_float4(0.f, 0.f, 0.f, 0.f);
    if (gy >= 0 && gy < HH && gx >= 0 && gx < WW)
      val = *(const float4*)(in + ((b * HH + gy) * WW + gx) * 64 + q * 4);
    *(float4*)&tile[p * 68 + q * 4] = val;
  }
  __syncthreads();

  int n = __builtin_amdgcn_readfirstlane(tid >> 6);  // wave id = output type
  int lane = tid & 63;
  int py = lane >> 3, px = lane & 7;
  int p0 = py * 10 + px;
  const float* wrep = ws + WREP_OFF;
  const float* arep = ws + AREP_OFF;

  float u[8][8];  // [d][c]
#pragma unroll
  for (int d = 0; d < 8; ++d)
#pragma unroll
    for (int c = 0; c < 8; ++c) u[d][c] = ctb[c * 64 + d * 8 + n];

#pragma unroll 1
  for (int k = 0; k < 9; ++k) {
    int kh = k / 3, kw = k % 3;
    int pb = (p0 + kh * 10 + kw) * 68;
    const float* wp = wrep + (n * 9 + k) * 512;  // [dd][c][d]
#pragma unroll
    for (int dd = 0; dd < 8; ++dd) {
      float4 xa = *(const float4*)&tile[pb + dd * 8];
      float4 xb = *(const float4*)&tile[pb + dd * 8 + 4];
      float xs[8] = {xa.x, xa.y, xa.z, xa.w, xb.x, xb.y, xb.z, xb.w};
#pragma unroll
      for (int c = 0; c < 8; ++c)
#pragma unroll
        for (int d = 0; d < 8; ++d)
          u[d][c] = fmaf(xs[c], wp[(dd * 8 + c) * 8 + d], u[d][c]);
    }
  }

  float att[8];
#pragma unroll
  for (int o = 0; o < 8; ++o) {
    const float* ap = arep + (n * 8 + o) * 64;
    float s = 0.f;
#pragma unroll
    for (int d = 0; d < 8; ++d)
#pragma unroll
      for (int c = 0; c < 8; ++c) s = fmaf(u[d][c], ap[d * 8 + c], s);
    att[o] = s;
  }
  float m = att[0];
#pragma unroll
  for (int o = 1; o < 8; ++o) m = fmaxf(m, att[o]);
  float ssum = 0.f;
#pragma unroll
  for (int o = 0; o < 8; ++o) { att[o] = __expf(att[o] - m); ssum += att[o]; }
  float inv = 1.0f / ssum;
#pragma unroll
  for (int o = 0; o < 8; ++o) att[o] *= inv;

  F4H8 vo;
#pragma unroll
  for (int d = 0; d < 8; ++d) {
    float s = 0.f;
#pragma unroll
    for (int c = 0; c < 8; ++c) s = fmaf(u[d][c], att[c], s);
    vo.h[d] = __float2half(s);
  }

  // transpose through LDS (reuse tile), then fully-coalesced fp16 stores
  __syncthreads();
  float4* hb = (float4*)tile;  // chunk = 8 halves = 16B; pixel stride 8 chunks
  hb[lane * 8 + ((n + lane) & 7)] = vo.f4;  // XOR-swizzled: b128-floor banks
  __syncthreads();

  {
    int p = tid >> 3, q = tid & 7;  // pixel, channel-chunk
    float4 val = hb[p * 8 + ((q + p) & 7)];
    int gp = ((b * HH + ty * 8 + (p >> 3)) * WW + tx * 8 + (p & 7));
    ((float4*)(vt + gp * 64))[q] = val;
  }
}

// Stage 2: FeaExt (3x3 grouped) + ReLU + CapsAct (1x1 grouped) -> out (fp32)
// 512 threads = 8 waves; wave w owns n=w. fp16 input tile, fp32 compute.
__global__ __launch_bounds__(512, 6) void caps_stage2(
    const __half* __restrict__ vt, const float* __restrict__ ws,
    const float* __restrict__ fb, const float* __restrict__ cab,
    float* __restrict__ out) {
  __shared__ float smem[64 * 68];  // 17.4 KB; aliased as fp16 tile then fp32 out-buf
  int bid = blockIdx.x;
  int b = bid >> 6;
  int t = bid & 63;
  int ty = t >> 3, tx = t & 7;
  int y0 = ty * 8 - 1, x0 = tx * 8 - 1;
  int tid = threadIdx.x;

  float4* ht = (float4*)smem;  // 100 px x 8 chunks (8 halves each), XOR-swizzled
  for (int i = tid; i < 800; i += 512) {
    int p = i >> 3, q = i & 7;
    int py = p / 10, px = p % 10;
    int gy = y0 + py, gx = x0 + px;
    float4 val = make_float4(0.f, 0.f, 0.f, 0.f);
    if (gy >= 0 && gy < HH && gx >= 0 && gx < WW)
      val = ((const float4*)(vt + ((b * HH + gy) * WW + gx) * 64))[q];
    ht[p * 8 + ((q + p) & 7)] = val;
  }
  __syncthreads();

  int n = __builtin_amdgcn_readfirstlane(tid >> 6);
  int lane = tid & 63;
  int py = lane >> 3, px = lane & 7;
  int p0 = py * 10 + px;
  const float* fwrep = ws + FWREP_OFF;
  const float* cwrep = ws + CWREP_OFF;

  float h1[8];
#pragma unroll
  for (int j = 0; j < 8; ++j) h1[j] = fb[n * 8 + j];

#pragma unroll 1
  for (int k = 0; k < 9; ++k) {
    int kh = k / 3, kw = k % 3;
    int pk = p0 + kh * 10 + kw;
    const float* wp = fwrep + (n * 9 + k) * 64;  // [d][j]
    F4H8 xu;
    xu.f4 = ht[pk * 8 + ((n + pk) & 7)];
#pragma unroll
    for (int d = 0; d < 8; ++d) {
      float xv = __half2float(xu.h[d]);
#pragma unroll
      for (int j = 0; j < 8; ++j)
        h1[j] = fmaf(xv, wp[d * 8 + j], h1[j]);
    }
  }
#pragma unroll
  for (int j = 0; j < 8; ++j) h1[j] = fmaxf(h1[j], 0.f);

  float h2[8];
#pragma unroll
  for (int j = 0; j < 8; ++j) h2[j] = cab[n * 8 + j];
#pragma unroll
  for (int d = 0; d < 8; ++d)
#pragma unroll
    for (int j = 0; j < 8; ++j)
      h2[j] = fmaf(h1[d], cwrep[n * 64 + d * 8 + j], h2[j]);

  // transpose h2 through LDS (fp32), coalesced float4 stores
  __syncthreads();
#pragma unroll
  for (int j = 0; j < 8; ++j) {
    int mch = 2 * j + (n >> 2);  // float4-chunk of out channel j*8+n
    smem[lane * 64 + ((mch + lane) & 15) * 4 + (n & 3)] = h2[j];
  }
  __syncthreads();

  for (int s = tid; s < 1024; s += 512) {
    int p = s >> 4, q = s & 15;
    float4 val = *(float4*)&smem[p * 64 + ((q + p) & 15) * 4];
    int gp = ((b * HH + ty * 8 + (p >> 3)) * WW + tx * 8 + (p & 7));
    *(float4*)(out + gp * 64 + q * 4) = val;
  }
}

extern "C" void kernel_launch(void* const* d_in, const int* in_sizes, int n_in,
                              void* d_out, int out_size, void* d_ws, size_t ws_size,
                              hipStream_t stream) {
  const float* inputs = (const float*)d_in[0];
  const float* attw   = (const float*)d_in[1];
  const float* ctw    = (const float*)d_in[2];
  const float* ctb    = (const float*)d_in[3];
  const float* few    = (const float*)d_in[4];
  const float* fb     = (const float*)d_in[5];
  const float* caw    = (const float*)d_in[6];
  const float* cab    = (const float*)d_in[7];
  float* out = (float*)d_out;
  float* ws  = (float*)d_ws;
  __half* vt = (__half*)(ws + VT_OFF);

  prep_kernel<<<(PREP_N + 255) / 256, 256, 0, stream>>>(attw, ctw, few, caw, ws);
  caps_stage1<<<32 * 64, 512, 0, stream>>>(inputs, ws, ctb, vt);
  caps_stage2<<<32 * 64, 512, 0, stream>>>(vt, ws, fb, cab, out);
}

// Round 4
// 152.225 us; speedup vs baseline: 1.7926x; 1.6684x over previous
//
#include <hip/hip_runtime.h>
#include <hip/hip_fp16.h>

#define HH 64
#define WW 64

typedef short bf16x8 __attribute__((ext_vector_type(8)));
typedef float f32x4 __attribute__((ext_vector_type(4)));
typedef unsigned short u16x8 __attribute__((ext_vector_type(8)));

// ws float offsets
#define FWREP_OFF 0         // [n*9+k][slot*8+j] : 4608 floats (slot-permuted d)
#define CWREP_OFF 4608      // [n][d][j] : 512
#define LBIAS_OFF 5120      // [col=s*16+l15] : 64
#define M1REP_OFF 5184      // bf16 [(c*12+r*4+s)*64+lane][j] : 49152 halves
#define BUREP_OFF 29760     // bf16 same shape : 49152 halves
#define VT_OFF    54336     // fp16 [pixel][n][slot] : 131072*64 halves
#define PREP_N    103488

__device__ __forceinline__ unsigned short f2bf(float x) {
  unsigned int u = __float_as_uint(x);
  return (unsigned short)((u + 0x7FFFu + ((u >> 16) & 1u)) >> 16);
}
__device__ __forceinline__ unsigned short f2h(float x) {
  return __half_as_ushort(__float2half(x));
}

union F4H8 { float4 f4; __half h[8]; };

__global__ __launch_bounds__(256) void prep_kernel(
    const float* __restrict__ attw, const float* __restrict__ ctw,
    const float* __restrict__ ctb, const float* __restrict__ few,
    const float* __restrict__ caw, float* __restrict__ ws) {
  int i = blockIdx.x * 256 + threadIdx.x;
  if (i >= PREP_N) return;
  if (i < 4608) {
    // fwrep[n][k][slot][j] = few[k, dperm(slot), n*8+j]
    int e = i & 63, slot = e >> 3, j = e & 7;
    int k = (i >> 6) % 9, n = i / 576;
    int d = 2 * (slot & 3) + (slot >> 2);
    ws[FWREP_OFF + i] = few[(k * 8 + d) * 64 + n * 8 + j];
  } else if (i < 5120) {
    int z = i - 4608;
    int j = z & 7, d = (z >> 3) & 7, n = (z >> 6) & 7;
    ws[CWREP_OFF + z] = caw[d * 64 + n * 8 + j];
  } else if (i < 5184) {
    // logits bias: Lb[col] = sum_{d,c} ctb[c,d,n]*attw[d,c,n,o]
    int col = i - 5120;
    int s = col >> 4, l15 = col & 15;
    int o = 2 * s + (l15 >> 3), n = l15 & 7;
    float acc = 0.f;
    for (int c = 0; c < 8; ++c)
      for (int d = 0; d < 8; ++d)
        acc += ctb[c * 64 + d * 8 + n] * attw[d * 512 + c * 64 + n * 8 + o];
    ws[LBIAS_OFF + col] = acc;
  } else if (i < 5184 + 49152) {
    // M1 fragments: M1[kappa=(c,t,dd)][col=(o,n)] = sum_d W*Aatt, taps>=9 zero
    int z = i - 5184;
    int j = z & 7, lane = (z >> 3) & 63, s = (z >> 9) & 3;
    int rc = z >> 11, r = rc % 3, c = rc / 3;
    int q = lane >> 4, l15 = lane & 15;
    int t = r * 4 + q, dd = j;
    int o = 2 * s + (l15 >> 3), n = l15 & 7;
    float acc = 0.f;
    if (t < 9)
      for (int d = 0; d < 8; ++d)
        acc += ctw[(t * 8 + dd) * 512 + c * 64 + d * 8 + n] *
               attw[d * 512 + c * 64 + n * 8 + o];
    ((unsigned short*)(ws + M1REP_OFF))[z] = f2bf(acc);
  } else {
    // Bu fragments: Bu[kappa=(c,t,dd)][col=(d,n)] = W, taps>=9 zero
    int z = i - 5184 - 49152;
    int j = z & 7, lane = (z >> 3) & 63, s = (z >> 9) & 3;
    int rc = z >> 11, r = rc % 3, c = rc / 3;
    int q = lane >> 4, l15 = lane & 15;
    int t = r * 4 + q, dd = j;
    int d = 2 * s + (l15 >> 3), n = l15 & 7;
    float val = (t < 9) ? ctw[(t * 8 + dd) * 512 + c * 64 + d * 8 + n] : 0.f;
    ((unsigned short*)(ws + BUREP_OFF))[z] = f2bf(val);
  }
}

// Stage 1 (MFMA): logits -> softmax (in-register) -> u-conv -> v  => vt fp16
// Block 256 = 4 waves; pixel tile 16(y) x 8(x) = 128 px; wave w owns Mtiles {2w,2w+1}.
__global__ __launch_bounds__(256, 2) void caps_stage1(
    const float* __restrict__ in, const float* __restrict__ ws,
    const float* __restrict__ ctb, __half* __restrict__ vt) {
  __shared__ unsigned short xt[181 * 72];    // bf16 [halo px][c*8+dd], hp=180 zero slot
  __shared__ unsigned short attb[128 * 72];  // fp16 [p][n*8+o]
  int bid = blockIdx.x;
  int b = bid >> 5;
  int t5 = bid & 31;
  int ty = t5 >> 3, tx = t5 & 7;  // ty 0..3 (16-row), tx 0..7 (8-col)
  int tid = threadIdx.x;

  // ---- fill x tile (fp32 -> bf16, transpose d,c) ----
  for (int i = tid; i < 181 * 8; i += 256) {
    int c = i & 7, hp = i >> 3;
    float xs[8] = {0.f, 0.f, 0.f, 0.f, 0.f, 0.f, 0.f, 0.f};
    if (hp < 180) {
      int hy = hp / 10, hx = hp - hy * 10;
      int gy = ty * 16 + hy - 1, gx = tx * 8 + hx - 1;
      if (gy >= 0 && gy < HH && gx >= 0 && gx < WW) {
        const float* src = in + (((b * HH + gy) * WW + gx) * 64 + c);
#pragma unroll
        for (int d = 0; d < 8; ++d) xs[d] = src[d * 8];
      }
    }
    u16x8 pk;
#pragma unroll
    for (int d = 0; d < 8; ++d) pk[d] = f2bf(xs[d]);
    *(u16x8*)&xt[hp * 72 + c * 8] = pk;
  }
  __syncthreads();

  int w = __builtin_amdgcn_readfirstlane(tid >> 6);
  int lane = tid & 63;
  int q = lane >> 4, l15 = lane & 15;
  int h = l15 >> 3, n = l15 & 7;

  // A-fragment halo addresses (halves offset), per (i2, Ktile r); tap t = r*4+q
  int hpt[2][3];
#pragma unroll
  for (int i2 = 0; i2 < 2; ++i2) {
    int pyA = (2 * w + i2) * 2 + h;  // ((mta*16 + l15)>>3)
    int pxA = l15 & 7;
#pragma unroll
    for (int r = 0; r < 3; ++r) {
      int t = r * 4 + q;
      int hp;
      if (t < 9) {
        int ky = t / 3, kx = t - ky * 3;
        hp = (pyA + ky) * 10 + pxA + kx;
      } else {
        hp = 180;
      }
      hpt[i2][r] = hp * 72;
    }
  }

  const bf16x8* m1v = (const bf16x8*)(ws + M1REP_OFF);
  const bf16x8* buv = (const bf16x8*)(ws + BUREP_OFF);
  const float* lb = ws + LBIAS_OFF;

  // ---- pass 1: attention logits via MFMA ----
  f32x4 L[2][4];
#pragma unroll
  for (int s = 0; s < 4; ++s) {
    float v0 = lb[s * 16 + l15];
    L[0][s] = (f32x4){v0, v0, v0, v0};
    L[1][s] = (f32x4){v0, v0, v0, v0};
  }
#pragma unroll 1
  for (int c = 0; c < 8; ++c) {
    bf16x8 bm[12];
#pragma unroll
    for (int rs = 0; rs < 12; ++rs) bm[rs] = m1v[(c * 12 + rs) * 64 + lane];
    bf16x8 a[2][3];
#pragma unroll
    for (int i2 = 0; i2 < 2; ++i2)
#pragma unroll
      for (int r = 0; r < 3; ++r)
        a[i2][r] = *(const bf16x8*)&xt[hpt[i2][r] + c * 8];
#pragma unroll
    for (int i2 = 0; i2 < 2; ++i2)
#pragma unroll
      for (int s = 0; s < 4; ++s)
#pragma unroll
        for (int r = 0; r < 3; ++r)
          L[i2][s] = __builtin_amdgcn_mfma_f32_16x16x32_bf16(
              a[i2][r], bm[r * 4 + s], L[i2][s], 0, 0, 0);
  }

  // ---- softmax over o (4 s-frags in-lane + lane^8), write att to LDS ----
#pragma unroll
  for (int i2 = 0; i2 < 2; ++i2) {
    int pbase = (2 * w + i2) * 16 + q * 4;
#pragma unroll
    for (int r = 0; r < 4; ++r) {
      float v0 = L[i2][0][r], v1 = L[i2][1][r], v2 = L[i2][2][r], v3 = L[i2][3][r];
      float pm = fmaxf(fmaxf(v0, v1), fmaxf(v2, v3));
      float m = fmaxf(pm, __shfl_xor(pm, 8));
      float e0 = __expf(v0 - m), e1 = __expf(v1 - m);
      float e2 = __expf(v2 - m), e3 = __expf(v3 - m);
      float ps = e0 + e1 + e2 + e3;
      float inv = 1.f / (ps + __shfl_xor(ps, 8));
      int ab = (pbase + r) * 72 + n * 8 + h;  // o = 2s + h
      attb[ab + 0] = f2h(e0 * inv);
      attb[ab + 2] = f2h(e1 * inv);
      attb[ab + 4] = f2h(e2 * inv);
      attb[ab + 6] = f2h(e3 * inv);
    }
  }
  __syncthreads();

  // ---- pass 2: u-conv per c (MFMA) + fold attention -> v ----
  u16x8 atp[2][4];
#pragma unroll
  for (int i2 = 0; i2 < 2; ++i2)
#pragma unroll
    for (int r = 0; r < 4; ++r)
      atp[i2][r] = *(const u16x8*)&attb[((2 * w + i2) * 16 + q * 4 + r) * 72 + n * 8];

  f32x4 V[2][4];
#pragma unroll
  for (int s = 0; s < 4; ++s) {
    V[0][s] = (f32x4){0.f, 0.f, 0.f, 0.f};
    V[1][s] = (f32x4){0.f, 0.f, 0.f, 0.f};
  }
#pragma unroll 1
  for (int c = 0; c < 8; ++c) {
    bf16x8 bu[12];
#pragma unroll
    for (int rs = 0; rs < 12; ++rs) bu[rs] = buv[(c * 12 + rs) * 64 + lane];
    bf16x8 a[2][3];
#pragma unroll
    for (int i2 = 0; i2 < 2; ++i2)
#pragma unroll
      for (int r = 0; r < 3; ++r)
        a[i2][r] = *(const bf16x8*)&xt[hpt[i2][r] + c * 8];
    f32x4 U[2][4];
#pragma unroll
    for (int s = 0; s < 4; ++s) {
      float bv = ctb[c * 64 + s * 16 + l15];
      U[0][s] = (f32x4){bv, bv, bv, bv};
      U[1][s] = (f32x4){bv, bv, bv, bv};
    }
#pragma unroll
    for (int i2 = 0; i2 < 2; ++i2)
#pragma unroll
      for (int s = 0; s < 4; ++s)
#pragma unroll
        for (int r = 0; r < 3; ++r)
          U[i2][s] = __builtin_amdgcn_mfma_f32_16x16x32_bf16(
              a[i2][r], bu[r * 4 + s], U[i2][s], 0, 0, 0);
#pragma unroll
    for (int i2 = 0; i2 < 2; ++i2)
#pragma unroll
      for (int r = 0; r < 4; ++r) {
        float af = __half2float(__ushort_as_half(atp[i2][r][c]));
#pragma unroll
        for (int s = 0; s < 4; ++s) V[i2][s][r] += U[i2][s][r] * af;
      }
  }

  // ---- store v -> vt [pixel][n][slot] fp16, slot = h*4+s (d = 2s+h) ----
#pragma unroll
  for (int i2 = 0; i2 < 2; ++i2)
#pragma unroll
    for (int r = 0; r < 4; ++r) {
      int p = (2 * w + i2) * 16 + q * 4 + r;
      int gy = ty * 16 + (p >> 3), gx = tx * 8 + (p & 7);
      size_t gp = (size_t)((b * HH + gy) * WW + gx);
      short4 st;
      st.x = (short)f2h(V[i2][0][r]);
      st.y = (short)f2h(V[i2][1][r]);
      st.z = (short)f2h(V[i2][2][r]);
      st.w = (short)f2h(V[i2][3][r]);
      *(short4*)((char*)vt + gp * 128 + n * 16 + h * 8) = st;
    }
}

// Stage 2: FeaExt (3x3 grouped) + ReLU + CapsAct (1x1 grouped) -> out (fp32)
// vt slot order absorbed by fwrep permutation in prep.
__global__ __launch_bounds__(512, 6) void caps_stage2(
    const __half* __restrict__ vt, const float* __restrict__ ws,
    const float* __restrict__ fb, const float* __restrict__ cab,
    float* __restrict__ out) {
  __shared__ float smem[64 * 68];
  int bid = blockIdx.x;
  int b = bid >> 6;
  int t = bid & 63;
  int ty = t >> 3, tx = t & 7;
  int y0 = ty * 8 - 1, x0 = tx * 8 - 1;
  int tid = threadIdx.x;

  float4* ht = (float4*)smem;  // 100 px x 8 chunks (8 halves), XOR-swizzled
  for (int i = tid; i < 800; i += 512) {
    int p = i >> 3, q = i & 7;
    int py = p / 10, px = p % 10;
    int gy = y0 + py, gx = x0 + px;
    float4 val = make_float4(0.f, 0.f, 0.f, 0.f);
    if (gy >= 0 && gy < HH && gx >= 0 && gx < WW)
      val = ((const float4*)(vt + ((b * HH + gy) * WW + gx) * 64))[q];
    ht[p * 8 + ((q + p) & 7)] = val;
  }
  __syncthreads();

  int n = __builtin_amdgcn_readfirstlane(tid >> 6);
  int lane = tid & 63;
  int py = lane >> 3, px = lane & 7;
  int p0 = py * 10 + px;
  const float* fwrep = ws + FWREP_OFF;
  const float* cwrep = ws + CWREP_OFF;

  float h1[8];
#pragma unroll
  for (int j = 0; j < 8; ++j) h1[j] = fb[n * 8 + j];

#pragma unroll 1
  for (int k = 0; k < 9; ++k) {
    int kh = k / 3, kw = k % 3;
    int pk = p0 + kh * 10 + kw;
    const float* wp = fwrep + (n * 9 + k) * 64;  // [slot][j]
    F4H8 xu;
    xu.f4 = ht[pk * 8 + ((n + pk) & 7)];
#pragma unroll
    for (int d = 0; d < 8; ++d) {
      float xv = __half2float(xu.h[d]);
#pragma unroll
      for (int j = 0; j < 8; ++j)
        h1[j] = fmaf(xv, wp[d * 8 + j], h1[j]);
    }
  }
#pragma unroll
  for (int j = 0; j < 8; ++j) h1[j] = fmaxf(h1[j], 0.f);

  float h2[8];
#pragma unroll
  for (int j = 0; j < 8; ++j) h2[j] = cab[n * 8 + j];
#pragma unroll
  for (int d = 0; d < 8; ++d)
#pragma unroll
    for (int j = 0; j < 8; ++j)
      h2[j] = fmaf(h1[d], cwrep[n * 64 + d * 8 + j], h2[j]);

  __syncthreads();
#pragma unroll
  for (int j = 0; j < 8; ++j) {
    int mch = 2 * j + (n >> 2);
    smem[lane * 64 + ((mch + lane) & 15) * 4 + (n & 3)] = h2[j];
  }
  __syncthreads();

  for (int s = tid; s < 1024; s += 512) {
    int p = s >> 4, q = s & 15;
    float4 val = *(float4*)&smem[p * 64 + ((q + p) & 15) * 4];
    int gp = ((b * HH + ty * 8 + (p >> 3)) * WW + tx * 8 + (p & 7));
    *(float4*)(out + gp * 64 + q * 4) = val;
  }
}

extern "C" void kernel_launch(void* const* d_in, const int* in_sizes, int n_in,
                              void* d_out, int out_size, void* d_ws, size_t ws_size,
                              hipStream_t stream) {
  const float* inputs = (const float*)d_in[0];
  const float* attw   = (const float*)d_in[1];
  const float* ctw    = (const float*)d_in[2];
  const float* ctb    = (const float*)d_in[3];
  const float* few    = (const float*)d_in[4];
  const float* fb     = (const float*)d_in[5];
  const float* caw    = (const float*)d_in[6];
  const float* cab    = (const float*)d_in[7];
  float* out = (float*)d_out;
  float* ws  = (float*)d_ws;
  __half* vt = (__half*)(ws + VT_OFF);

  prep_kernel<<<(PREP_N + 255) / 256, 256, 0, stream>>>(attw, ctw, ctb, few, caw, ws);
  caps_stage1<<<32 * 32, 256, 0, stream>>>(inputs, ws, ctb, vt);
  caps_stage2<<<32 * 64, 512, 0, stream>>>(vt, ws, fb, cab, out);
}